// Round 15
// baseline (61.986 us; speedup 1.0000x reference)
//
#include <hip/hip_runtime.h>

// attn [B=64, N=1024, N=1024] f32. Per (b, k=1..1022): unbiased std of the
// k-th super-diagonal scaled by (N-k)/5; mean over k then b -> scalar.
//
// R15: clean contiguity probe. Block (b, u) reads 64 CONSECUTIVE top rows
// [64u,64u+64) interleaved with 64 consecutive bottom rows [960-64u,..)
// (active lanes per row pair sum to ~256 -> balanced). Consecutive rows'
// diagonal segments are adjacent in memory -> ~256KB near-sequential stream
// per block. Thread t keeps 7 static k-bins (k-4t in 1..7): row with phase
// P covers bins P-1..P+2 at literal indices (4-row macro, compile-time).
// One LDS resolve (R12's verified <=2-contributor mapping) -> plain
// k-indexed partials; ws = 4.2 MB and grid = 512, IDENTICAL to R14 -- only
// the read ORDER differs. Pass 2 (NB*16): sum 8 u-chunks at k, std, block
// reduce. Pass 3: fixed-order reduce. 3-kernel structure mandatory (R10).

#define NN 1024
#define NB 64
#define WP 1032   // per-chunk section width

__global__ __launch_bounds__(256) void diag_pass1(
    const float* __restrict__ attn, float* __restrict__ ws) {
  const int b = blockIdx.x >> 3;    // sample
  const int u = blockIdx.x & 7;     // row-band pair id
  const int t = threadIdx.x;
  const float* __restrict__ base = attn + ((size_t)b << 20);

  const int topi = 64 * u;          // top band: rows topi..topi+63
  const int boti = 960 - 64 * u;    // bottom band: rows boti..boti+63

  float s1[7] = {0.f,0.f,0.f,0.f,0.f,0.f,0.f};
  float s2[7] = {0.f,0.f,0.f,0.f,0.f,0.f,0.f};

  // Row i with literal phase P (= (-i) mod 4, 0->4): quad at k0 = P+4t,
  // flat addr i*1025 + k0 (16B-aligned since i+P === 0 mod 4). Valid iff
  // 4t < 1024-i-P (all-or-nothing: 1024-i === P mod 4). Bins P-1..P+2.
#define ROW1(i, P)                                                        \
  {                                                                       \
    const int lim = 1024 - (i) - (P);                                     \
    if (4 * t < lim) {                                                    \
      const float4 v = *reinterpret_cast<const float4*>(                  \
          base + (size_t)(i) * 1025 + (P) + 4 * t);                       \
      s1[(P) - 1] += v.x; s2[(P) - 1] += v.x * v.x;                       \
      s1[(P)    ] += v.y; s2[(P)    ] += v.y * v.y;                       \
      s1[(P) + 1] += v.z; s2[(P) + 1] += v.z * v.z;                       \
      s1[(P) + 2] += v.w; s2[(P) + 2] += v.w * v.w;                       \
    }                                                                     \
  }
#define ROW4(i0)                                                          \
  { ROW1((i0), 4) ROW1((i0) + 1, 3) ROW1((i0) + 2, 2) ROW1((i0) + 3, 1) }

  #pragma unroll 2
  for (int g = 0; g < 16; ++g) {    // interleave top/bottom 4-row groups
    ROW4(topi + 4 * g)
    ROW4(boti + 4 * g)
  }
#undef ROW4
#undef ROW1

  // Stage bins; wave 3 gathers the 192 edge elements (k < P per row).
  __shared__ float L1[7 * 256], L2[7 * 256];
  __shared__ float Eb[8];           // [1..3]=sum, [5..7]=sumsq
  #pragma unroll
  for (int bq = 0; bq < 7; ++bq) {
    L1[bq * 256 + t] = s1[bq];
    L2[bq * 256 + t] = s2[bq];
  }

  if (t >= 192) {                   // wave 3; 3 entries per lane
    const int l = t - 192;
    float E11 = 0.f, E12 = 0.f, E13 = 0.f;
    float E21 = 0.f, E22 = 0.f, E23 = 0.f;
    #pragma unroll
    for (int h = 0; h < 3; ++h) {
      const int m = l + 64 * h;     // 0..191
      const int grp = m / 6;        // 0..31 (16 top + 16 bottom 4-row groups)
      const int idx = m % 6;        // (dr,ee): p=4 row -> k=1,2,3; p=3 -> 1,2; p=2 -> 1
      const int dr = idx < 3 ? 0 : (idx < 5 ? 1 : 2);
      const int ee = idx < 3 ? idx + 1 : (idx < 5 ? idx - 2 : 1);
      const int i = (grp < 16 ? topi + 4 * grp : boti + 4 * (grp - 16)) + dr;
      float x = 0.f;
      if (i + ee < 1024) x = base[(size_t)i * 1025 + ee];
      const float xx = x * x;
      if (ee == 1)      { E11 += x; E21 += xx; }
      else if (ee == 2) { E12 += x; E22 += xx; }
      else              { E13 += x; E23 += xx; }
    }
    #pragma unroll
    for (int s = 1; s < 64; s <<= 1) {
      E11 += __shfl_xor(E11, s); E21 += __shfl_xor(E21, s);
      E12 += __shfl_xor(E12, s); E22 += __shfl_xor(E22, s);
      E13 += __shfl_xor(E13, s); E23 += __shfl_xor(E23, s);
    }
    if (l == 0) {
      Eb[1] = E11; Eb[2] = E12; Eb[3] = E13;
      Eb[5] = E21; Eb[6] = E22; Eb[7] = E23;
    }
  }
  __syncthreads();

  // Resolve bins -> plain k-indexed partials. k's contributors:
  // (bin b0=(k-1)&3, thread t0=(k-1)>>2) and (b0+4, t0-1) if b0<=2;
  // plus edge sums for k<=3.
  float* __restrict__ wout = ws + (size_t)blockIdx.x * (2 * WP);
  #pragma unroll
  for (int j = 0; j < 4; ++j) {
    const int k = 1 + t + 256 * j;
    if (k <= 1023) {
      const int b0 = (k - 1) & 3;
      const int t0 = (k - 1) >> 2;
      float v1 = L1[b0 * 256 + t0];
      float v2 = L2[b0 * 256 + t0];
      if (b0 <= 2 && t0 >= 1) {
        v1 += L1[(b0 + 4) * 256 + t0 - 1];
        v2 += L2[(b0 + 4) * 256 + t0 - 1];
      }
      if (k <= 3) { v1 += Eb[k]; v2 += Eb[4 + k]; }
      wout[k]      = v1;
      wout[WP + k] = v2;
    }
  }
}

// Block (b, kg): k = kg*64 + kk; cg = t>>6 sums u-chunks {cg, cg+4}.
__global__ __launch_bounds__(256) void diag_pass2(
    const float* __restrict__ ws, float* __restrict__ part) {
  const int b  = blockIdx.x >> 4;
  const int kg = blockIdx.x & 15;
  const int t  = threadIdx.x;
  const int kk = t & 63;
  const int cg = t >> 6;
  const int k  = kg * 64 + kk;

  float s1 = 0.f, s2 = 0.f;
  #pragma unroll
  for (int c = cg; c < 8; c += 4) {
    const float* __restrict__ w0 = ws + (size_t)(b * 8 + c) * (2 * WP);
    s1 += w0[k];
    s2 += w0[WP + k];
  }

  __shared__ float r1[256], r2[256];
  r1[t] = s1; r2[t] = s2;
  __syncthreads();
  if (t < 128) { r1[t] += r1[t + 128]; r2[t] += r2[t + 128]; }
  __syncthreads();
  if (t < 64) {
    s1 = r1[t] + r1[t + 64];
    s2 = r2[t] + r2[t + 64];
    float acc = 0.f;
    if (k >= 1 && k <= NN - 2) {
      const float n = (float)(NN - k);
      const float mean = s1 / n;
      const float var = fmaxf(s2 - n * mean * mean, 0.f) / (n - 1.f);
      acc = sqrtf(var) * (n * 0.2f);              // std * (N-k)/5
    }
    #pragma unroll
    for (int s = 32; s > 0; s >>= 1) acc += __shfl_down(acc, s);
    if (t == 0) part[blockIdx.x] = acc;
  }
}

__global__ __launch_bounds__(256) void diag_pass3(
    const float* __restrict__ part, float* __restrict__ out) {
  const int t = threadIdx.x;
  float v = part[t] + part[t + 256] + part[t + 512] + part[t + 768];
  __shared__ float red[256];
  red[t] = v;
  __syncthreads();
  #pragma unroll
  for (int s = 128; s > 0; s >>= 1) {
    if (t < s) red[t] += red[t + s];
    __syncthreads();
  }
  if (t == 0) out[0] = red[0] * (1.0f / (1022.0f * 64.0f));
}

extern "C" void kernel_launch(void* const* d_in, const int* in_sizes, int n_in,
                              void* d_out, int out_size, void* d_ws, size_t ws_size,
                              hipStream_t stream) {
  const float* attn = (const float*)d_in[0];
  float* out = (float*)d_out;
  float* ws = (float*)d_ws;

  float* part = ws + (size_t)NB * 8 * 2 * WP;     // 1024 f32 (after 4.2 MB)

  diag_pass1<<<NB * 8, 256, 0, stream>>>(attn, ws);
  diag_pass2<<<NB * 16, 256, 0, stream>>>(ws, part);
  diag_pass3<<<1, 256, 0, stream>>>(part, out);
}

// Round 16
// 49.224 us; speedup vs baseline: 1.2593x; 1.2593x over previous
//
#include <hip/hip_runtime.h>

// attn [B=64, N=1024, N=1024] f32. Per (b, k=1..1022): unbiased std of the
// k-th super-diagonal scaled by (N-k)/5; mean over k then b -> scalar.
//
// R16 = R14 (champion, 36.7us) + ONE change: nontemporal loads in the two
// quad hot loops (streaming 134MB with zero reuse -> skip L2 allocation;
// partial-sum stores stay cached for pass 2). Tests the last unfalsified
// theory: L2 read-allocate pollution caps the diagonal read at ~4.3 TB/s.
//
// Pass 1 (grid NB*8, 256 thr): chunk-paired complementary quad pairing.
// Block (b,c0) covers c-sets {c0, c0+8} (same phase); thread t owns quad
// k0=p+4t (first half of valid rows) and quad 255-t (second half), per
// c-set. Phase alignment -> all loads unconditional. B-partials folded via
// 8KB LDS exchange; ws [sum][sq] x W per block (4.2 MB total).
// Pass 2 (grid NB*16): sum 8 chunks at phase-relative idx, std, block
// reduce -> part[1024]. Pass 3: fixed-order reduce. 3 kernels mandatory
// (R10: fused epilogue +29us). Read order: 9 variants bracket ~4.3 TB/s.

#define NN 1024
#define NB 64
#define W 1032   // section stride: 1024 slots + 3 edge + pad

typedef float f4v __attribute__((ext_vector_type(4)));

__global__ __launch_bounds__(256) void diag_pass1(
    const float* __restrict__ attn, float* __restrict__ ws) {
  const int b  = blockIdx.x >> 3;   // sample
  const int c0 = blockIdx.x & 7;    // chunk pair: covers c0 and c0+8
  const int t  = threadIdx.x;
  int p = (4 - (c0 & 3)) & 3; if (p == 0) p = 4;  // k = p+4t is 16B-aligned

  const float* __restrict__ base = attn + ((size_t)b << 20);
  const size_t stride = (size_t)16 * (NN + 1);    // rows within a c-set

  const int qB = 255 - t;
  float a1x=0.f,a1y=0.f,a1z=0.f,a1w=0.f,a2x=0.f,a2y=0.f,a2z=0.f,a2w=0.f;
  float b1x=0.f,b1y=0.f,b1z=0.f,b1w=0.f,b2x=0.f,b2y=0.f,b2z=0.f,b2w=0.f;

  #pragma unroll
  for (int h = 0; h < 2; ++h) {
    const int c = c0 + 8 * h;
    const float* __restrict__ rowc = base + (size_t)c * (NN + 1);

    // Quad A = t: rows m in [0, SaA)  (first half of its valid range)
    const int dfA = 1020 - c - p - 4 * t;         // full-valid iff 16m <= dfA
    const int TfA = (dfA >= 0) ? ((dfA >> 4) + 1) : 0;
    const int SaA = (TfA + 1) >> 1;
    {
      const float* ptr = rowc + (p + 4 * t);
      #pragma unroll 8
      for (int m = 0; m < SaA; ++m) {
        const f4v v = __builtin_nontemporal_load(
            reinterpret_cast<const f4v*>(ptr + (size_t)m * stride));
        a1x += v.x; a2x += v.x * v.x;
        a1y += v.y; a2y += v.y * v.y;
        a1z += v.z; a2z += v.z * v.z;
        a1w += v.w; a2w += v.w * v.w;
      }
    }

    // Quad B = 255-t: rows m in [SaB, TfB)  (second half of ITS range)
    const int dfB = 4 * t - c - p;                // = 1020-c-p-4*qB
    const int TfB = (dfB >= 0) ? ((dfB >> 4) + 1) : 0;
    const int SaB = (TfB + 1) >> 1;
    {
      const float* ptr = rowc + (p + 4 * qB);
      #pragma unroll 8
      for (int m = SaB; m < TfB; ++m) {
        const f4v v = __builtin_nontemporal_load(
            reinterpret_cast<const f4v*>(ptr + (size_t)m * stride));
        b1x += v.x; b2x += v.x * v.x;
        b1y += v.y; b2y += v.y * v.y;
        b1z += v.z; b2z += v.z * v.z;
        b1w += v.w; b2w += v.w * v.w;
      }
    }
  }

  // Fold: LDS slot q holds B-partials of quad q (written by thread 255-q).
  __shared__ float4 lb1[256], lb2[256];
  lb1[qB] = make_float4(b1x, b1y, b1z, b1w);
  lb2[qB] = make_float4(b2x, b2y, b2z, b2w);
  __syncthreads();
  const float4 f1 = lb1[t];
  const float4 f2 = lb2[t];
  a1x += f1.x; a1y += f1.y; a1z += f1.z; a1w += f1.w;
  a2x += f2.x; a2y += f2.y; a2z += f2.z; a2w += f2.w;

  float* __restrict__ w1 = ws + (size_t)blockIdx.x * (2 * W);
  *reinterpret_cast<float4*>(w1 + 4 * t)     = make_float4(a1x,a1y,a1z,a1w);
  *reinterpret_cast<float4*>(w1 + W + 4 * t) = make_float4(a2x,a2y,a2z,a2w);

  // Edge columns k = 1..p-1: wave w==e, one row per lane, both c-sets.
  const int e = t >> 6;
  if (e >= 1 && e < p) {
    const int l = t & 63;
    float e1 = 0.f, e2 = 0.f;
    #pragma unroll
    for (int h = 0; h < 2; ++h) {
      const int i = c0 + 8 * h + 16 * l;          // 64 rows per c-set
      if (i + e < NN) {
        const float x = base[(size_t)i * (NN + 1) + e];
        e1 += x; e2 += x * x;
      }
    }
    #pragma unroll
    for (int s = 1; s < 64; s <<= 1) {
      e1 += __shfl_xor(e1, s);
      e2 += __shfl_xor(e2, s);
    }
    if (l == 0) {
      w1[1024 + e]     = e1;
      w1[W + 1024 + e] = e2;
    }
  }
}

// Block (b, kg): k = kg*64 + kk; cg = t>>6 sums chunks c = cg, cg+4.
__global__ __launch_bounds__(256) void diag_pass2(
    const float* __restrict__ ws, float* __restrict__ part) {
  const int b  = blockIdx.x >> 4;
  const int kg = blockIdx.x & 15;
  const int t  = threadIdx.x;
  const int kk = t & 63;
  const int cg = t >> 6;
  const int k  = kg * 64 + kk;

  int p = (4 - cg) & 3; if (p == 0) p = 4;        // phase for chunk c = cg mod 4
  const int idx = (k >= p) ? (k - p) : (1024 + k);

  float s1 = 0.f, s2 = 0.f;
  #pragma unroll
  for (int c = cg; c < 8; c += 4) {
    const float* __restrict__ w0 = ws + (size_t)(b * 8 + c) * (2 * W);
    s1 += w0[idx];
    s2 += w0[W + idx];
  }

  __shared__ float r1[256], r2[256];
  r1[t] = s1; r2[t] = s2;
  __syncthreads();
  if (t < 128) { r1[t] += r1[t + 128]; r2[t] += r2[t + 128]; }
  __syncthreads();
  if (t < 64) {
    s1 = r1[t] + r1[t + 64];
    s2 = r2[t] + r2[t + 64];
    float acc = 0.f;
    if (k >= 1 && k <= NN - 2) {
      const float n = (float)(NN - k);
      const float mean = s1 / n;
      const float var = fmaxf(s2 - n * mean * mean, 0.f) / (n - 1.f);
      acc = sqrtf(var) * (n * 0.2f);              // std * (N-k)/5
    }
    #pragma unroll
    for (int s = 32; s > 0; s >>= 1) acc += __shfl_down(acc, s);
    if (t == 0) part[blockIdx.x] = acc;
  }
}

__global__ __launch_bounds__(256) void diag_pass3(
    const float* __restrict__ part, float* __restrict__ out) {
  const int t = threadIdx.x;
  float v = part[t] + part[t + 256] + part[t + 512] + part[t + 768];
  __shared__ float red[256];
  red[t] = v;
  __syncthreads();
  #pragma unroll
  for (int s = 128; s > 0; s >>= 1) {
    if (t < s) red[t] += red[t + s];
    __syncthreads();
  }
  if (t == 0) out[0] = red[0] * (1.0f / (1022.0f * 64.0f));
}

extern "C" void kernel_launch(void* const* d_in, const int* in_sizes, int n_in,
                              void* d_out, int out_size, void* d_ws, size_t ws_size,
                              hipStream_t stream) {
  const float* attn = (const float*)d_in[0];
  float* out = (float*)d_out;
  float* ws = (float*)d_ws;

  float* part = ws + (size_t)NB * 8 * 2 * W;      // 1024 f32 (after 4.2 MB)

  diag_pass1<<<NB * 8, 256, 0, stream>>>(attn, ws);
  diag_pass2<<<NB * 16, 256, 0, stream>>>(ws, part);
  diag_pass3<<<1, 256, 0, stream>>>(part, out);
}

// Round 17
// 36.634 us; speedup vs baseline: 1.6921x; 1.3437x over previous
//
#include <hip/hip_runtime.h>

// attn [B=64, N=1024, N=1024] f32. Per (b, k=1..1022): unbiased std of the
// k-th super-diagonal scaled by (N-k)/5; mean over k then b -> scalar.
//
// R17 = R14 champion, byte-identical resubmission (R16's NT-load probe
// regressed -12.5us: L2 read-allocate HELPS this pattern).
//
// Final structure, with the full falsification ledger in the session log:
// Pass 1 (grid NB*8, 256 thr): chunk-paired complementary quad pairing.
// Block (b,c0) covers row-sets {i===c0 mod 16} and {i===c0+8 mod 16} (same
// phase p). Thread t owns quad k0=p+4t (FIRST half of its valid rows) and
// quad 255-t (SECOND half); trip counts sum ~64 -> all waves dense to the
// end (R8's +2.4us win over triangular decay). Phase alignment -> every
// quad row-wise all-or-nothing valid -> zero masked loads. B-partials
// folded via 8KB LDS exchange (R13 +3us); chunk pairs halve ws again
// (R14 +0.8us; ws = 4.2MB). Diagonal-segment read: ~4.3 TB/s bracketed
// by 9 structural variants (ILP/TLP/stride/contiguity/NT all falsified).
// Edge columns k=1..p-1: wave e, one row per lane, shfl reduce.
// Pass 2 (grid NB*16): sum 8 chunks at phase-relative idx, std formula,
// block reduce -> part[1024]. Pass 3 (1 block): fixed-order reduce.
// 3-kernel structure mandatory (R10: fused last-block epilogue +29us).

#define NN 1024
#define NB 64
#define W 1032   // section stride: 1024 slots + 3 edge + pad

__global__ __launch_bounds__(256) void diag_pass1(
    const float* __restrict__ attn, float* __restrict__ ws) {
  const int b  = blockIdx.x >> 3;   // sample
  const int c0 = blockIdx.x & 7;    // chunk pair: covers c0 and c0+8
  const int t  = threadIdx.x;
  int p = (4 - (c0 & 3)) & 3; if (p == 0) p = 4;  // k = p+4t is 16B-aligned

  const float* __restrict__ base = attn + ((size_t)b << 20);
  const size_t stride = (size_t)16 * (NN + 1);    // rows within a c-set

  const int qB = 255 - t;
  float a1x=0.f,a1y=0.f,a1z=0.f,a1w=0.f,a2x=0.f,a2y=0.f,a2z=0.f,a2w=0.f;
  float b1x=0.f,b1y=0.f,b1z=0.f,b1w=0.f,b2x=0.f,b2y=0.f,b2z=0.f,b2w=0.f;

  #pragma unroll
  for (int h = 0; h < 2; ++h) {
    const int c = c0 + 8 * h;
    const float* __restrict__ rowc = base + (size_t)c * (NN + 1);

    // Quad A = t: rows m in [0, SaA)  (first half of its valid range)
    const int dfA = 1020 - c - p - 4 * t;         // full-valid iff 16m <= dfA
    const int TfA = (dfA >= 0) ? ((dfA >> 4) + 1) : 0;
    const int SaA = (TfA + 1) >> 1;
    {
      const float* ptr = rowc + (p + 4 * t);
      #pragma unroll 8
      for (int m = 0; m < SaA; ++m) {
        const float4 v = *reinterpret_cast<const float4*>(ptr + (size_t)m * stride);
        a1x += v.x; a2x += v.x * v.x;
        a1y += v.y; a2y += v.y * v.y;
        a1z += v.z; a2z += v.z * v.z;
        a1w += v.w; a2w += v.w * v.w;
      }
    }

    // Quad B = 255-t: rows m in [SaB, TfB)  (second half of ITS range)
    const int dfB = 4 * t - c - p;                // = 1020-c-p-4*qB
    const int TfB = (dfB >= 0) ? ((dfB >> 4) + 1) : 0;
    const int SaB = (TfB + 1) >> 1;
    {
      const float* ptr = rowc + (p + 4 * qB);
      #pragma unroll 8
      for (int m = SaB; m < TfB; ++m) {
        const float4 v = *reinterpret_cast<const float4*>(ptr + (size_t)m * stride);
        b1x += v.x; b2x += v.x * v.x;
        b1y += v.y; b2y += v.y * v.y;
        b1z += v.z; b2z += v.z * v.z;
        b1w += v.w; b2w += v.w * v.w;
      }
    }
  }

  // Fold: LDS slot q holds B-partials of quad q (written by thread 255-q).
  __shared__ float4 lb1[256], lb2[256];
  lb1[qB] = make_float4(b1x, b1y, b1z, b1w);
  lb2[qB] = make_float4(b2x, b2y, b2z, b2w);
  __syncthreads();
  const float4 f1 = lb1[t];
  const float4 f2 = lb2[t];
  a1x += f1.x; a1y += f1.y; a1z += f1.z; a1w += f1.w;
  a2x += f2.x; a2y += f2.y; a2z += f2.z; a2w += f2.w;

  float* __restrict__ w1 = ws + (size_t)blockIdx.x * (2 * W);
  *reinterpret_cast<float4*>(w1 + 4 * t)     = make_float4(a1x,a1y,a1z,a1w);
  *reinterpret_cast<float4*>(w1 + W + 4 * t) = make_float4(a2x,a2y,a2z,a2w);

  // Edge columns k = 1..p-1: wave w==e, one row per lane, both c-sets.
  const int e = t >> 6;
  if (e >= 1 && e < p) {
    const int l = t & 63;
    float e1 = 0.f, e2 = 0.f;
    #pragma unroll
    for (int h = 0; h < 2; ++h) {
      const int i = c0 + 8 * h + 16 * l;          // 64 rows per c-set
      if (i + e < NN) {
        const float x = base[(size_t)i * (NN + 1) + e];
        e1 += x; e2 += x * x;
      }
    }
    #pragma unroll
    for (int s = 1; s < 64; s <<= 1) {
      e1 += __shfl_xor(e1, s);
      e2 += __shfl_xor(e2, s);
    }
    if (l == 0) {
      w1[1024 + e]     = e1;
      w1[W + 1024 + e] = e2;
    }
  }
}

// Block (b, kg): k = kg*64 + kk; cg = t>>6 sums chunks c = cg, cg+4.
__global__ __launch_bounds__(256) void diag_pass2(
    const float* __restrict__ ws, float* __restrict__ part) {
  const int b  = blockIdx.x >> 4;
  const int kg = blockIdx.x & 15;
  const int t  = threadIdx.x;
  const int kk = t & 63;
  const int cg = t >> 6;
  const int k  = kg * 64 + kk;

  int p = (4 - cg) & 3; if (p == 0) p = 4;        // phase for chunk c = cg mod 4
  const int idx = (k >= p) ? (k - p) : (1024 + k);

  float s1 = 0.f, s2 = 0.f;
  #pragma unroll
  for (int c = cg; c < 8; c += 4) {
    const float* __restrict__ w0 = ws + (size_t)(b * 8 + c) * (2 * W);
    s1 += w0[idx];
    s2 += w0[W + idx];
  }

  __shared__ float r1[256], r2[256];
  r1[t] = s1; r2[t] = s2;
  __syncthreads();
  if (t < 128) { r1[t] += r1[t + 128]; r2[t] += r2[t + 128]; }
  __syncthreads();
  if (t < 64) {
    s1 = r1[t] + r1[t + 64];
    s2 = r2[t] + r2[t + 64];
    float acc = 0.f;
    if (k >= 1 && k <= NN - 2) {
      const float n = (float)(NN - k);
      const float mean = s1 / n;
      const float var = fmaxf(s2 - n * mean * mean, 0.f) / (n - 1.f);
      acc = sqrtf(var) * (n * 0.2f);              // std * (N-k)/5
    }
    #pragma unroll
    for (int s = 32; s > 0; s >>= 1) acc += __shfl_down(acc, s);
    if (t == 0) part[blockIdx.x] = acc;
  }
}

__global__ __launch_bounds__(256) void diag_pass3(
    const float* __restrict__ part, float* __restrict__ out) {
  const int t = threadIdx.x;
  float v = part[t] + part[t + 256] + part[t + 512] + part[t + 768];
  __shared__ float red[256];
  red[t] = v;
  __syncthreads();
  #pragma unroll
  for (int s = 128; s > 0; s >>= 1) {
    if (t < s) red[t] += red[t + s];
    __syncthreads();
  }
  if (t == 0) out[0] = red[0] * (1.0f / (1022.0f * 64.0f));
}

extern "C" void kernel_launch(void* const* d_in, const int* in_sizes, int n_in,
                              void* d_out, int out_size, void* d_ws, size_t ws_size,
                              hipStream_t stream) {
  const float* attn = (const float*)d_in[0];
  float* out = (float*)d_out;
  float* ws = (float*)d_ws;

  float* part = ws + (size_t)NB * 8 * 2 * W;      // 1024 f32 (after 4.2 MB)

  diag_pass1<<<NB * 8, 256, 0, stream>>>(attn, ws);
  diag_pass2<<<NB * 16, 256, 0, stream>>>(ws, part);
  diag_pass3<<<1, 256, 0, stream>>>(part, out);
}